// Round 13
// baseline (174.299 us; speedup 1.0000x reference)
//
#include <hip/hip_runtime.h>
#include <stdint.h>

typedef _Float16 half8 __attribute__((ext_vector_type(8)));
typedef float floatx4 __attribute__((ext_vector_type(4)));
typedef float fvec4 __attribute__((ext_vector_type(4)));
typedef float fvec2 __attribute__((ext_vector_type(2)));

struct WPtrs { const float *wc, *wn, *wp, *we; };

// ---------------------------------------------------------------------------
// Prep kernel: grid = [norm blocks | 4 psi blocks]
//  - norm: x rows -> unit fp16 xhat (pure streaming, no LDS)
//  - psi: Wc+Wn normalized+scaled (fp16, MFMA B layout) for k_main
// ---------------------------------------------------------------------------
struct PrepArgs {
  const float* x; _Float16* xhat; int N; int nb_norm;
  WPtrs w[4]; _Float16* psi;
};

__global__ __launch_bounds__(256) void k_prep(PrepArgs a) {
  int bid = blockIdx.x, tid = threadIdx.x;

  if (bid < a.nb_norm) {
    int row = bid * 64 + (tid >> 2);
    int q   = tid & 3;
    if (row >= a.N) return;
    const fvec4* xr = reinterpret_cast<const fvec4*>(a.x + (size_t)row * 32 + q * 8);
    fvec4 va = __builtin_nontemporal_load(xr);
    fvec4 vb = __builtin_nontemporal_load(xr + 1);
    float ss = va[0] * va[0] + va[1] * va[1] + va[2] * va[2] + va[3] * va[3] +
               vb[0] * vb[0] + vb[1] * vb[1] + vb[2] * vb[2] + vb[3] * vb[3];
    ss += __shfl_xor(ss, 1);
    ss += __shfl_xor(ss, 2);
    float rn = ss > 0.f ? rsqrtf(ss) : 0.f;
    half8 h;
    h[0] = (_Float16)(va[0] * rn); h[1] = (_Float16)(va[1] * rn);
    h[2] = (_Float16)(va[2] * rn); h[3] = (_Float16)(va[3] * rn);
    h[4] = (_Float16)(vb[0] * rn); h[5] = (_Float16)(vb[1] * rn);
    h[6] = (_Float16)(vb[2] * rn); h[7] = (_Float16)(vb[3] * rn);
    *reinterpret_cast<half8*>(a.xhat + (size_t)row * 32 + q * 8) = h;
    return;
  }

  // ---- pack Wc + Wn into psi: row k = [wc(32) | wn_s(32)*d], fp16 ----
  int g = bid - a.nb_norm;         // 0..3
  int d = g + 1;
  int KD = 32 * (1 + d);
  _Float16* pg = a.psi + (size_t)g * (16 * 160);

  int k     = tid & 15;
  int piece = tid >> 4;
  if (piece > d) return;
  const float* src;
  float scale;
  if (piece == 0) { src = a.w[g].wc + k * 32;                           scale = 0.25f; }
  else            { src = a.w[g].wn + (size_t)(k * d + piece - 1) * 32; scale = 0.25f / d; }
  float ss = 0.f;
  for (int j = 0; j < 32; ++j) ss += src[j] * src[j];
  float sc = ss > 0.f ? scale * rsqrtf(ss) : 0.f;
  _Float16* dst = pg + k * KD + 32 * piece;
  for (int j = 0; j < 32; ++j) dst[j] = (_Float16)(src[j] * sc);
}

// ---------------------------------------------------------------------------
// Main kernel: fully fused. Block covers 64*NCH CONTIGUOUS nodes.
//  phase A: each thread stages its own nodes' p/e slots (coalesced NT loads,
//           rsqrt normalize, fp16 pack) into an LDS A-panel.
//  phase B: indices + xhat gathers issued (independent of LDS).
//  __syncthreads.
//  phase C: per chunk: acc = pe-MFMAs (A from LDS, B per-lane regs) +
//           xhat-MFMAs (psi B).
//  writeback: per (chunk,j): 1 NT dword score store (all lanes) +
//           1 NT dwordx4 zero store (lanes r<12 cover the 3 zero regions).
// MFMA 16x16x32 f16:  A row = lane&15, B col = lane&15, k-chunk = lane>>4.
// C/D: col = lane&15, row = (lane>>4)*4 + reg  [verified layout].
// ---------------------------------------------------------------------------
struct MainArgs {
  const _Float16* xhat;
  const _Float16* psi;       // group g at psi + g*16*160, row stride KD(g)
  const int* sel[4];
  const int* nei[4];
  const float* p[4];
  const float* e[4];
  WPtrs w[4];
  float* out;
  int nd[4];
  int blkOff[5];             // cumulative block offsets per group
};

template <int D, int NCH>
__device__ inline void main_one(const MainArgs& a, int g, int blk,
                                _Float16* lds) {
  constexpr int NF  = 1 + D;            // xhat fragments
  constexpr int KD  = 32 * NF;
  constexpr int K16 = 16 * D;
  constexpr int K32 = ((D + 1) / 2) * 32;
  constexpr int NM  = K32 / 32;         // pe MFMAs per chunk
  constexpr int RS  = K32 + 8;          // LDS row stride (halves)
  constexpr int NN  = 64 * NCH;         // nodes per block

  const _Float16* xhat = a.xhat;
  const _Float16* psi  = a.psi + (size_t)g * (16 * 160);
  const int* sel = a.sel[g];
  const int* nei = a.nei[g];
  const float* __restrict__ pptr = a.p[g];
  const float* __restrict__ eptr = a.e[g];
  int nd = a.nd[g];

  int tid  = threadIdx.x;
  int wave = tid >> 6, lane = tid & 63;
  int r = lane & 15, c = lane >> 4;
  int nchunks = (nd + 15) >> 4;
  size_t base = (size_t)blk * NN;

  // ---- phase A: stage this block's p/e nodes into LDS (NT streaming) ----
  for (int l = tid; l < NN; l += 256) {
    size_t node = base + l;
    size_t nc = node < (size_t)nd ? node : (size_t)(nd - 1);
    _Float16* arow = lds + (size_t)l * RS;
    float pf[3 * D];
    if constexpr (D == 4) {
      const fvec4* pv = reinterpret_cast<const fvec4*>(pptr + nc * 12);
#pragma unroll
      for (int t = 0; t < 3; ++t) {
        fvec4 v = __builtin_nontemporal_load(pv + t);
        pf[t * 4 + 0] = v[0]; pf[t * 4 + 1] = v[1];
        pf[t * 4 + 2] = v[2]; pf[t * 4 + 3] = v[3];
      }
    } else if constexpr (D == 2) {
      const fvec2* pv = reinterpret_cast<const fvec2*>(pptr + nc * 6);
#pragma unroll
      for (int t = 0; t < 3; ++t) {
        fvec2 v = __builtin_nontemporal_load(pv + t);
        pf[t * 2 + 0] = v[0]; pf[t * 2 + 1] = v[1];
      }
    } else {
      const float* pp = pptr + nc * 3 * D;
#pragma unroll
      for (int t = 0; t < 3 * D; ++t) pf[t] = __builtin_nontemporal_load(pp + t);
    }
#pragma unroll
    for (int s = 0; s < D; ++s) {
      float a0 = pf[s * 3 + 0], a1 = pf[s * 3 + 1], a2 = pf[s * 3 + 2];
      float s1 = a0 * a0 + a1 * a1 + a2 * a2;
      float r1 = s1 > 0.f ? rsqrtf(s1) : 0.f;
      const fvec4* ee = reinterpret_cast<const fvec4*>(eptr + (nc * D + s) * 8);
      fvec4 e0 = __builtin_nontemporal_load(ee);
      fvec4 e1 = __builtin_nontemporal_load(ee + 1);
      float s2 = e0[0] * e0[0] + e0[1] * e0[1] + e0[2] * e0[2] + e0[3] * e0[3] +
                 e1[0] * e1[0] + e1[1] * e1[1] + e1[2] * e1[2] + e1[3] * e1[3];
      float r2 = s2 > 0.f ? rsqrtf(s2) : 0.f;
      half8 h0, h1;
      h0[0] = (_Float16)(a0 * r1); h0[1] = (_Float16)(a1 * r1);
      h0[2] = (_Float16)(a2 * r1); h0[3] = (_Float16)0.f;
      h0[4] = (_Float16)(e0[0] * r2); h0[5] = (_Float16)(e0[1] * r2);
      h0[6] = (_Float16)(e0[2] * r2); h0[7] = (_Float16)(e0[3] * r2);
      h1[0] = (_Float16)(e1[0] * r2); h1[1] = (_Float16)(e1[1] * r2);
      h1[2] = (_Float16)(e1[2] * r2); h1[3] = (_Float16)(e1[3] * r2);
      h1[4] = (_Float16)0.f; h1[5] = (_Float16)0.f;
      h1[6] = (_Float16)0.f; h1[7] = (_Float16)0.f;
      *reinterpret_cast<half8*>(arow + s * 16)     = h0;
      *reinterpret_cast<half8*>(arow + s * 16 + 8) = h1;
    }
    if (K32 > K16) {
      half8 z = {};
      *reinterpret_cast<half8*>(arow + K16)     = z;
      *reinterpret_cast<half8*>(arow + K16 + 8) = z;
    }
  }

  // ---- B fragments (xhat path from psi; pe path per-lane from weights) ----
  half8 bx[NF];
  {
    const _Float16* pb = psi + (size_t)r * KD + c * 8;
#pragma unroll
    for (int t = 0; t < NF; ++t)
      bx[t] = *reinterpret_cast<const half8*>(pb + 32 * t);
  }
  half8 bpe[NM];
#pragma unroll
  for (int m = 0; m < NM; ++m) {
    int s = 2 * m + (c >> 1);
    if (s < D) {
      const float* sp = a.w[g].wp + ((size_t)r * D + s) * 3;
      float a0 = sp[0], a1 = sp[1], a2 = sp[2];
      float q1 = a0 * a0 + a1 * a1 + a2 * a2;
      float s1 = q1 > 0.f ? 0.25f / D * rsqrtf(q1) : 0.f;
      const float* se = a.w[g].we + ((size_t)r * D + s) * 8;
      float b0 = se[0], b1 = se[1], b2 = se[2], b3 = se[3];
      float b4 = se[4], b5 = se[5], b6 = se[6], b7 = se[7];
      float q2 = b0 * b0 + b1 * b1 + b2 * b2 + b3 * b3 +
                 b4 * b4 + b5 * b5 + b6 * b6 + b7 * b7;
      float s2 = q2 > 0.f ? 0.25f / D * rsqrtf(q2) : 0.f;
      half8 h;
      if ((c & 1) == 0) {
        h[0] = (_Float16)(a0 * s1); h[1] = (_Float16)(a1 * s1);
        h[2] = (_Float16)(a2 * s1); h[3] = (_Float16)0.f;
        h[4] = (_Float16)(b0 * s2); h[5] = (_Float16)(b1 * s2);
        h[6] = (_Float16)(b2 * s2); h[7] = (_Float16)(b3 * s2);
      } else {
        h[0] = (_Float16)(b4 * s2); h[1] = (_Float16)(b5 * s2);
        h[2] = (_Float16)(b6 * s2); h[3] = (_Float16)(b7 * s2);
        h[4] = (_Float16)0.f; h[5] = (_Float16)0.f;
        h[6] = (_Float16)0.f; h[7] = (_Float16)0.f;
      }
      bpe[m] = h;
    } else {
      bpe[m] = half8{};
    }
  }

  // ---- phase B: indices + xhat gathers (no LDS dependence) ----
  int sidx[NCH];
  int gidx[NCH][D];
#pragma unroll
  for (int u = 0; u < NCH; ++u) {
    int ri = (int)base + (wave * NCH + u) * 16 + r;
    if (ri > nd - 1) ri = nd - 1;
    sidx[u] = sel[ri];
#pragma unroll
    for (int s = 0; s < D; ++s)
      gidx[u][s] = nei[(size_t)ri * D + s];
  }
  half8 af[NCH][NF];
#pragma unroll
  for (int u = 0; u < NCH; ++u) {
    af[u][0] = *reinterpret_cast<const half8*>(xhat + (size_t)sidx[u] * 32 + c * 8);
#pragma unroll
    for (int s = 0; s < D; ++s)
      af[u][1 + s] = *reinterpret_cast<const half8*>(xhat + (size_t)gidx[u][s] * 32 + c * 8);
  }

  __syncthreads();

  // ---- phase C: MFMAs + writeback ----
  // zero-store lane mapping: lanes r<12 cover the 3 zero regions of node
  // n(c,j): region rho = r>>2 -> out region q = rho + (rho >= D-1),
  // 16B segment (r&3) -> contiguous 64B per region across 4 lanes.
  int zr = r >> 2;
  int zregion = zr + (zr >= (D - 1) ? 1 : 0);
  fvec4 zv = {0.f, 0.f, 0.f, 0.f};

#pragma unroll
  for (int u = 0; u < NCH; ++u) {
    floatx4 acc = {0.f, 0.f, 0.f, 0.f};
    const _Float16* arow = lds + (size_t)((wave * NCH + u) * 16 + r) * RS + c * 8;
#pragma unroll
    for (int m = 0; m < NM; ++m) {
      half8 ap = *reinterpret_cast<const half8*>(arow + m * 32);
      acc = __builtin_amdgcn_mfma_f32_16x16x32_f16(ap, bpe[m], acc, 0, 0, 0);
    }
#pragma unroll
    for (int t = 0; t < NF; ++t)
      acc = __builtin_amdgcn_mfma_f32_16x16x32_f16(af[u][t], bx[t], acc, 0, 0, 0);

    int chunk = blk * (4 * NCH) + wave * NCH + u;
    if (chunk < nchunks) {
      int i0 = chunk << 4;
#pragma unroll
      for (int j = 0; j < 4; ++j) {
        int n  = i0 + c * 4 + j;
        int so = __shfl(sidx[u], c * 4 + j);  // sel[i0 + c*4 + j]
        if (n < nd) {
          float* orow = a.out + (size_t)so * 64;
          // score: col r of region D-1 (all 16 r-lanes per node)
          __builtin_nontemporal_store(acc[j], orow + (D - 1) * 16 + r);
          // zeros: 3 regions x 64B, 12 lanes x dwordx4
          if (r < 12)
            __builtin_nontemporal_store(
                zv, reinterpret_cast<fvec4*>(orow + zregion * 16 + (r & 3) * 4));
        }
      }
    }
  }
}

__global__ __launch_bounds__(256) void k_main(MainArgs a) {
  __shared__ __align__(16) _Float16 lds[15360];  // max: 384 rows * 40 halves
  int bid = blockIdx.x;
  if (bid < a.blkOff[1])      main_one<1, 6>(a, 0, bid,               lds);
  else if (bid < a.blkOff[2]) main_one<2, 5>(a, 1, bid - a.blkOff[1], lds);
  else if (bid < a.blkOff[3]) main_one<3, 3>(a, 2, bid - a.blkOff[2], lds);
  else                        main_one<4, 3>(a, 3, bid - a.blkOff[3], lds);
}

// ---------------------------------------------------------------------------
extern "C" void kernel_launch(void* const* d_in, const int* in_sizes, int n_in,
                              void* d_out, int out_size, void* d_ws, size_t ws_size,
                              hipStream_t stream) {
  const float* x = (const float*)d_in[0];
  int N = in_sizes[0] / 32;

  PrepArgs pa;
  MainArgs ma;
  pa.x = x; pa.N = N;
  int nd[4];
  for (int g = 0; g < 4; ++g) {
    int b = 1 + g * 8;
    ma.sel[g]  = (const int*)d_in[b + 0];
    ma.nei[g]  = (const int*)d_in[b + 1];
    ma.p[g]    = (const float*)d_in[b + 2];
    ma.e[g]    = (const float*)d_in[b + 3];
    pa.w[g].wc = (const float*)d_in[b + 4];
    pa.w[g].wn = (const float*)d_in[b + 5];
    pa.w[g].wp = (const float*)d_in[b + 6];
    pa.w[g].we = (const float*)d_in[b + 7];
    ma.w[g]    = pa.w[g];
    nd[g] = in_sizes[b];
    ma.nd[g] = nd[g];
  }
  ma.out = (float*)d_out;

  // workspace layout: xhat | psi
  char* ws = (char*)d_ws;
  auto align256 = [](size_t o) { return (o + 255) & ~(size_t)255; };
  _Float16* xhat = (_Float16*)ws;
  size_t off = align256((size_t)N * 32 * 2);
  _Float16* psi = (_Float16*)(ws + off);
  pa.xhat = xhat;
  pa.psi  = psi;
  ma.xhat = xhat;
  ma.psi  = psi;

  // prep grid: [norm | 4 psi blocks]
  pa.nb_norm = (N + 63) / 64;
  int prep_blocks = pa.nb_norm + 4;

  // main grid: per-group block counts (4*NCH chunks per block)
  const int NCHg[4] = {6, 5, 3, 3};
  ma.blkOff[0] = 0;
  for (int g = 0; g < 4; ++g) {
    int ch = (nd[g] + 15) / 16;
    int perBlk = 4 * NCHg[g];
    ma.blkOff[g + 1] = ma.blkOff[g] + (ch + perBlk - 1) / perBlk;
  }

  k_prep<<<prep_blocks, 256, 0, stream>>>(pa);
  k_main<<<ma.blkOff[4], 256, 0, stream>>>(ma);
}

// Round 15
// 166.503 us; speedup vs baseline: 1.0468x; 1.0468x over previous
//
#include <hip/hip_runtime.h>
#include <stdint.h>

typedef _Float16 half8 __attribute__((ext_vector_type(8)));
typedef float floatx4 __attribute__((ext_vector_type(4)));
typedef float fvec4 __attribute__((ext_vector_type(4)));
typedef float fvec2 __attribute__((ext_vector_type(2)));

struct WPtrs { const float *wc, *wn, *wp, *we; };

// ---------------------------------------------------------------------------
// Prep kernel: grid = [norm blocks | 4 psi blocks]
//  - norm: x rows -> unit fp16 xhat (pure streaming, no LDS)
//  - psi: Wc+Wn normalized+scaled (fp16, MFMA B layout) for k_main
// ---------------------------------------------------------------------------
struct PrepArgs {
  const float* x; _Float16* xhat; int N; int nb_norm;
  WPtrs w[4]; _Float16* psi;
};

__global__ __launch_bounds__(256) void k_prep(PrepArgs a) {
  int bid = blockIdx.x, tid = threadIdx.x;

  if (bid < a.nb_norm) {
    int row = bid * 64 + (tid >> 2);
    int q   = tid & 3;
    if (row >= a.N) return;
    const fvec4* xr = reinterpret_cast<const fvec4*>(a.x + (size_t)row * 32 + q * 8);
    fvec4 va = xr[0], vb = xr[1];
    float ss = va[0] * va[0] + va[1] * va[1] + va[2] * va[2] + va[3] * va[3] +
               vb[0] * vb[0] + vb[1] * vb[1] + vb[2] * vb[2] + vb[3] * vb[3];
    ss += __shfl_xor(ss, 1);
    ss += __shfl_xor(ss, 2);
    float rn = ss > 0.f ? rsqrtf(ss) : 0.f;
    half8 h;
    h[0] = (_Float16)(va[0] * rn); h[1] = (_Float16)(va[1] * rn);
    h[2] = (_Float16)(va[2] * rn); h[3] = (_Float16)(va[3] * rn);
    h[4] = (_Float16)(vb[0] * rn); h[5] = (_Float16)(vb[1] * rn);
    h[6] = (_Float16)(vb[2] * rn); h[7] = (_Float16)(vb[3] * rn);
    *reinterpret_cast<half8*>(a.xhat + (size_t)row * 32 + q * 8) = h;
    return;
  }

  // ---- pack Wc + Wn into psi: row k = [wc(32) | wn_s(32)*d], fp16 ----
  int g = bid - a.nb_norm;         // 0..3
  int d = g + 1;
  int KD = 32 * (1 + d);
  _Float16* pg = a.psi + (size_t)g * (16 * 160);

  int k     = tid & 15;
  int piece = tid >> 4;
  if (piece > d) return;
  const float* src;
  float scale;
  if (piece == 0) { src = a.w[g].wc + k * 32;                           scale = 0.25f; }
  else            { src = a.w[g].wn + (size_t)(k * d + piece - 1) * 32; scale = 0.25f / d; }
  float ss = 0.f;
  for (int j = 0; j < 32; ++j) ss += src[j] * src[j];
  float sc = ss > 0.f ? scale * rsqrtf(ss) : 0.f;
  _Float16* dst = pg + k * KD + 32 * piece;
  for (int j = 0; j < 32; ++j) dst[j] = (_Float16)(src[j] * sc);
}

// ---------------------------------------------------------------------------
// Main kernel: fully fused. Block covers 64*NCH CONTIGUOUS nodes.
//  phase A: each thread stages its own nodes' p/e slots (coalesced cached
//           loads, rsqrt normalize, fp16 pack) into an LDS A-panel.
//  phase B: indices + xhat gathers issued (independent of LDS).
//  __syncthreads.
//  phase C: per chunk: acc = pe-MFMAs (A from LDS, B per-lane regs) +
//           xhat-MFMAs (psi B).
//  writeback (repacked): per (chunk,j): 1 dword score store (16 lanes) +
//           1 dwordx4 zero store (lanes r<12 cover the 3 zero regions).
// LDS budget (halves): D1/D2: 256*40=10240; D3/D4 (NCH=2): 128*72=9216.
// Static array 10240 halves = 20.5 KB -> 7 blocks/CU.
// MFMA 16x16x32 f16:  A row = lane&15, B col = lane&15, k-chunk = lane>>4.
// C/D: col = lane&15, row = (lane>>4)*4 + reg  [verified layout].
// ---------------------------------------------------------------------------
struct MainArgs {
  const _Float16* xhat;
  const _Float16* psi;       // group g at psi + g*16*160, row stride KD(g)
  const int* sel[4];
  const int* nei[4];
  const float* p[4];
  const float* e[4];
  WPtrs w[4];
  float* out;
  int nd[4];
  int blkOff[5];             // cumulative block offsets per group
};

template <int D, int NCH>
__device__ inline void main_one(const MainArgs& a, int g, int blk,
                                _Float16* lds) {
  constexpr int NF  = 1 + D;            // xhat fragments
  constexpr int KD  = 32 * NF;
  constexpr int K16 = 16 * D;
  constexpr int K32 = ((D + 1) / 2) * 32;
  constexpr int NM  = K32 / 32;         // pe MFMAs per chunk
  constexpr int RS  = K32 + 8;          // LDS row stride (halves)
  constexpr int NN  = 64 * NCH;         // nodes per block
  static_assert(NN * RS <= 10240, "LDS panel overflow");

  const _Float16* xhat = a.xhat;
  const _Float16* psi  = a.psi + (size_t)g * (16 * 160);
  const int* sel = a.sel[g];
  const int* nei = a.nei[g];
  const float* __restrict__ pptr = a.p[g];
  const float* __restrict__ eptr = a.e[g];
  int nd = a.nd[g];

  int tid  = threadIdx.x;
  int wave = tid >> 6, lane = tid & 63;
  int r = lane & 15, c = lane >> 4;
  int nchunks = (nd + 15) >> 4;
  size_t base = (size_t)blk * NN;

  // ---- phase A: stage this block's p/e nodes into LDS ----
  for (int l = tid; l < NN; l += 256) {
    size_t node = base + l;
    size_t nc = node < (size_t)nd ? node : (size_t)(nd - 1);
    _Float16* arow = lds + (size_t)l * RS;
    float pf[3 * D];
    if constexpr (D == 4) {
      const fvec4* pv = reinterpret_cast<const fvec4*>(pptr + nc * 12);
#pragma unroll
      for (int t = 0; t < 3; ++t) {
        fvec4 v = pv[t];
        pf[t * 4 + 0] = v[0]; pf[t * 4 + 1] = v[1];
        pf[t * 4 + 2] = v[2]; pf[t * 4 + 3] = v[3];
      }
    } else if constexpr (D == 2) {
      const fvec2* pv = reinterpret_cast<const fvec2*>(pptr + nc * 6);
#pragma unroll
      for (int t = 0; t < 3; ++t) {
        fvec2 v = pv[t];
        pf[t * 2 + 0] = v[0]; pf[t * 2 + 1] = v[1];
      }
    } else {
      const float* pp = pptr + nc * 3 * D;
#pragma unroll
      for (int t = 0; t < 3 * D; ++t) pf[t] = pp[t];
    }
#pragma unroll
    for (int s = 0; s < D; ++s) {
      float a0 = pf[s * 3 + 0], a1 = pf[s * 3 + 1], a2 = pf[s * 3 + 2];
      float s1 = a0 * a0 + a1 * a1 + a2 * a2;
      float r1 = s1 > 0.f ? rsqrtf(s1) : 0.f;
      const fvec4* ee = reinterpret_cast<const fvec4*>(eptr + (nc * D + s) * 8);
      fvec4 e0 = ee[0], e1 = ee[1];
      float s2 = e0[0] * e0[0] + e0[1] * e0[1] + e0[2] * e0[2] + e0[3] * e0[3] +
                 e1[0] * e1[0] + e1[1] * e1[1] + e1[2] * e1[2] + e1[3] * e1[3];
      float r2 = s2 > 0.f ? rsqrtf(s2) : 0.f;
      half8 h0, h1;
      h0[0] = (_Float16)(a0 * r1); h0[1] = (_Float16)(a1 * r1);
      h0[2] = (_Float16)(a2 * r1); h0[3] = (_Float16)0.f;
      h0[4] = (_Float16)(e0[0] * r2); h0[5] = (_Float16)(e0[1] * r2);
      h0[6] = (_Float16)(e0[2] * r2); h0[7] = (_Float16)(e0[3] * r2);
      h1[0] = (_Float16)(e1[0] * r2); h1[1] = (_Float16)(e1[1] * r2);
      h1[2] = (_Float16)(e1[2] * r2); h1[3] = (_Float16)(e1[3] * r2);
      h1[4] = (_Float16)0.f; h1[5] = (_Float16)0.f;
      h1[6] = (_Float16)0.f; h1[7] = (_Float16)0.f;
      *reinterpret_cast<half8*>(arow + s * 16)     = h0;
      *reinterpret_cast<half8*>(arow + s * 16 + 8) = h1;
    }
    if (K32 > K16) {
      half8 z = {};
      *reinterpret_cast<half8*>(arow + K16)     = z;
      *reinterpret_cast<half8*>(arow + K16 + 8) = z;
    }
  }

  // ---- B fragments (xhat path from psi; pe path per-lane from weights) ----
  half8 bx[NF];
  {
    const _Float16* pb = psi + (size_t)r * KD + c * 8;
#pragma unroll
    for (int t = 0; t < NF; ++t)
      bx[t] = *reinterpret_cast<const half8*>(pb + 32 * t);
  }
  half8 bpe[NM];
#pragma unroll
  for (int m = 0; m < NM; ++m) {
    int s = 2 * m + (c >> 1);
    if (s < D) {
      const float* sp = a.w[g].wp + ((size_t)r * D + s) * 3;
      float a0 = sp[0], a1 = sp[1], a2 = sp[2];
      float q1 = a0 * a0 + a1 * a1 + a2 * a2;
      float s1 = q1 > 0.f ? 0.25f / D * rsqrtf(q1) : 0.f;
      const float* se = a.w[g].we + ((size_t)r * D + s) * 8;
      float b0 = se[0], b1 = se[1], b2 = se[2], b3 = se[3];
      float b4 = se[4], b5 = se[5], b6 = se[6], b7 = se[7];
      float q2 = b0 * b0 + b1 * b1 + b2 * b2 + b3 * b3 +
                 b4 * b4 + b5 * b5 + b6 * b6 + b7 * b7;
      float s2 = q2 > 0.f ? 0.25f / D * rsqrtf(q2) : 0.f;
      half8 h;
      if ((c & 1) == 0) {
        h[0] = (_Float16)(a0 * s1); h[1] = (_Float16)(a1 * s1);
        h[2] = (_Float16)(a2 * s1); h[3] = (_Float16)0.f;
        h[4] = (_Float16)(b0 * s2); h[5] = (_Float16)(b1 * s2);
        h[6] = (_Float16)(b2 * s2); h[7] = (_Float16)(b3 * s2);
      } else {
        h[0] = (_Float16)(b4 * s2); h[1] = (_Float16)(b5 * s2);
        h[2] = (_Float16)(b6 * s2); h[3] = (_Float16)(b7 * s2);
        h[4] = (_Float16)0.f; h[5] = (_Float16)0.f;
        h[6] = (_Float16)0.f; h[7] = (_Float16)0.f;
      }
      bpe[m] = h;
    } else {
      bpe[m] = half8{};
    }
  }

  // ---- phase B: indices + xhat gathers (no LDS dependence) ----
  int sidx[NCH];
  int gidx[NCH][D];
#pragma unroll
  for (int u = 0; u < NCH; ++u) {
    int ri = (int)base + (wave * NCH + u) * 16 + r;
    if (ri > nd - 1) ri = nd - 1;
    sidx[u] = sel[ri];
#pragma unroll
    for (int s = 0; s < D; ++s)
      gidx[u][s] = nei[(size_t)ri * D + s];
  }
  half8 af[NCH][NF];
#pragma unroll
  for (int u = 0; u < NCH; ++u) {
    af[u][0] = *reinterpret_cast<const half8*>(xhat + (size_t)sidx[u] * 32 + c * 8);
#pragma unroll
    for (int s = 0; s < D; ++s)
      af[u][1 + s] = *reinterpret_cast<const half8*>(xhat + (size_t)gidx[u][s] * 32 + c * 8);
  }

  __syncthreads();

  // ---- phase C: MFMAs + writeback ----
  int zr = r >> 2;
  int zregion = zr + (zr >= (D - 1) ? 1 : 0);
  fvec4 zv = {0.f, 0.f, 0.f, 0.f};

#pragma unroll
  for (int u = 0; u < NCH; ++u) {
    floatx4 acc = {0.f, 0.f, 0.f, 0.f};
    const _Float16* arow = lds + (size_t)((wave * NCH + u) * 16 + r) * RS + c * 8;
#pragma unroll
    for (int m = 0; m < NM; ++m) {
      half8 ap = *reinterpret_cast<const half8*>(arow + m * 32);
      acc = __builtin_amdgcn_mfma_f32_16x16x32_f16(ap, bpe[m], acc, 0, 0, 0);
    }
#pragma unroll
    for (int t = 0; t < NF; ++t)
      acc = __builtin_amdgcn_mfma_f32_16x16x32_f16(af[u][t], bx[t], acc, 0, 0, 0);

    int chunk = blk * (4 * NCH) + wave * NCH + u;
    if (chunk < nchunks) {
      int i0 = chunk << 4;
#pragma unroll
      for (int j = 0; j < 4; ++j) {
        int n  = i0 + c * 4 + j;
        int so = __shfl(sidx[u], c * 4 + j);  // sel[i0 + c*4 + j]
        if (n < nd) {
          float* orow = a.out + (size_t)so * 64;
          orow[(D - 1) * 16 + r] = acc[j];                 // score col
          if (r < 12)                                      // 3 zero regions
            *reinterpret_cast<fvec4*>(orow + zregion * 16 + (r & 3) * 4) = zv;
        }
      }
    }
  }
}

__global__ __launch_bounds__(256) void k_main(MainArgs a) {
  __shared__ __align__(16) _Float16 lds[10240];  // 20.5 KB -> 7 blocks/CU
  int bid = blockIdx.x;
  if (bid < a.blkOff[1])      main_one<1, 4>(a, 0, bid,               lds);
  else if (bid < a.blkOff[2]) main_one<2, 4>(a, 1, bid - a.blkOff[1], lds);
  else if (bid < a.blkOff[3]) main_one<3, 2>(a, 2, bid - a.blkOff[2], lds);
  else                        main_one<4, 2>(a, 3, bid - a.blkOff[3], lds);
}

// ---------------------------------------------------------------------------
extern "C" void kernel_launch(void* const* d_in, const int* in_sizes, int n_in,
                              void* d_out, int out_size, void* d_ws, size_t ws_size,
                              hipStream_t stream) {
  const float* x = (const float*)d_in[0];
  int N = in_sizes[0] / 32;

  PrepArgs pa;
  MainArgs ma;
  pa.x = x; pa.N = N;
  int nd[4];
  for (int g = 0; g < 4; ++g) {
    int b = 1 + g * 8;
    ma.sel[g]  = (const int*)d_in[b + 0];
    ma.nei[g]  = (const int*)d_in[b + 1];
    ma.p[g]    = (const float*)d_in[b + 2];
    ma.e[g]    = (const float*)d_in[b + 3];
    pa.w[g].wc = (const float*)d_in[b + 4];
    pa.w[g].wn = (const float*)d_in[b + 5];
    pa.w[g].wp = (const float*)d_in[b + 6];
    pa.w[g].we = (const float*)d_in[b + 7];
    ma.w[g]    = pa.w[g];
    nd[g] = in_sizes[b];
    ma.nd[g] = nd[g];
  }
  ma.out = (float*)d_out;

  // workspace layout: xhat | psi
  char* ws = (char*)d_ws;
  auto align256 = [](size_t o) { return (o + 255) & ~(size_t)255; };
  _Float16* xhat = (_Float16*)ws;
  size_t off = align256((size_t)N * 32 * 2);
  _Float16* psi = (_Float16*)(ws + off);
  pa.xhat = xhat;
  pa.psi  = psi;
  ma.xhat = xhat;
  ma.psi  = psi;

  // prep grid: [norm | 4 psi blocks]
  pa.nb_norm = (N + 63) / 64;
  int prep_blocks = pa.nb_norm + 4;

  // main grid: per-group block counts (4*NCH chunks per block)
  const int NCHg[4] = {4, 4, 2, 2};
  ma.blkOff[0] = 0;
  for (int g = 0; g < 4; ++g) {
    int ch = (nd[g] + 15) / 16;
    int perBlk = 4 * NCHg[g];
    ma.blkOff[g + 1] = ma.blkOff[g] + (ch + perBlk - 1) / perBlk;
  }

  k_prep<<<prep_blocks, 256, 0, stream>>>(pa);
  k_main<<<ma.blkOff[4], 256, 0, stream>>>(ma);
}